// Round 6
// baseline (222.041 us; speedup 1.0000x reference)
//
#include <hip/hip_runtime.h>

#define SEQ 4096
#define DM  2048
#define DH  128

typedef __attribute__((ext_vector_type(8))) short bf16x8;
typedef __attribute__((ext_vector_type(4))) short short4v;
typedef __attribute__((ext_vector_type(4))) float f32x4;

__device__ inline short f2bf(float f) {
    union { float f; unsigned u; } x; x.f = f;
    unsigned r = x.u + 0x7fffu + ((x.u >> 16) & 1u);
    return (short)(r >> 16);
}

__device__ inline float fexp2(float f) { return __builtin_amdgcn_exp2f(f); }

// ---------------- W fp32 -> bf16 pre-convert. grid 768, block 256. Wbf[3][128][2048]
__global__ __launch_bounds__(256) void convw_kernel(
    const float* __restrict__ wq, const float* __restrict__ wk, const float* __restrict__ wv,
    short* __restrict__ Wbf)
{
    int idx = blockIdx.x * 256 + threadIdx.x;
    int mat = idx >> 16;
    int off = (idx & 65535) * 4;
    const float* W = (mat == 0) ? wq : (mat == 1) ? wk : wv;
    float4 v = *reinterpret_cast<const float4*>(W + off);
    short4v s = { f2bf(v.x), f2bf(v.y), f2bf(v.z), f2bf(v.w) };
    *reinterpret_cast<short4v*>(Wbf + (size_t)mat * DH * DM + off) = s;
}

// ---------------- Projection, split-K x2. grid (128, 3, 2), block 256 (4 waves).
// Block tile: 32 rows x 128 cols, K-range 1024, BK=64 (16 chunks).
// Depth-4 register prefetch for BOTH A (fp32, cvt on LDS write) and W (bf16).
__global__ __launch_bounds__(256) void proj_kernel(
    const float* __restrict__ inq, const float* __restrict__ ink, const float* __restrict__ inv,
    const short* __restrict__ Wbf,
    const float* __restrict__ bq, const float* __restrict__ bk, const float* __restrict__ bv,
    float* __restrict__ Pqk, float* __restrict__ Pv)
{
    const int mat = blockIdx.y;
    const int s   = blockIdx.z;
    const float* A    = (mat == 0) ? inq : (mat == 1) ? ink : inv;
    const float* bias = (mat == 0) ? bq : (mat == 1) ? bk : bv;

    const int tid  = threadIdx.x;
    const int lane = tid & 63;
    const int w    = tid >> 6;
    const int g    = lane >> 4;
    const int c16  = lane & 15;
    const int i0   = blockIdx.x * 32;
    const int kb   = s * 1024;

    __shared__ short Alds[32][72];
    __shared__ short Wlds[128][72];

    const int ar = tid >> 3, ac = (tid & 7) * 8;
    const float* Aload = A + (size_t)(i0 + ar) * DM + kb + ac;
    const int wr = tid >> 1, wc = (tid & 1) * 32;
    const short* Wload = Wbf + (size_t)mat * DH * DM + (size_t)wr * DM + kb + wc;

    f32x4 acc[4];
    #pragma unroll
    for (int n = 0; n < 4; n++) acc[n] = (f32x4){0.f, 0.f, 0.f, 0.f};

    float4  abuf[4][2];
    bf16x8  wbuf[4][4];

    #pragma unroll
    for (int d = 0; d < 4; d++) {
        #pragma unroll
        for (int j = 0; j < 4; j++)
            wbuf[d][j] = *reinterpret_cast<const bf16x8*>(Wload + d * 64 + j * 8);
        abuf[d][0] = *reinterpret_cast<const float4*>(Aload + d * 64);
        abuf[d][1] = *reinterpret_cast<const float4*>(Aload + d * 64 + 4);
    }

    const int arow = (w >> 1) * 16 + c16;
    const int wbase = (w & 1) * 64;

    #pragma unroll
    for (int c = 0; c < 16; c++) {
        const int d = c & 3;
        {
            short4v s0 = { f2bf(abuf[d][0].x), f2bf(abuf[d][0].y),
                           f2bf(abuf[d][0].z), f2bf(abuf[d][0].w) };
            short4v s1 = { f2bf(abuf[d][1].x), f2bf(abuf[d][1].y),
                           f2bf(abuf[d][1].z), f2bf(abuf[d][1].w) };
            *reinterpret_cast<short4v*>(&Alds[ar][ac])     = s0;
            *reinterpret_cast<short4v*>(&Alds[ar][ac + 4]) = s1;
            #pragma unroll
            for (int j = 0; j < 4; j++)
                *reinterpret_cast<bf16x8*>(&Wlds[wr][wc + j * 8]) = wbuf[d][j];
        }
        if (c + 4 < 16) {
            #pragma unroll
            for (int j = 0; j < 4; j++)
                wbuf[d][j] = *reinterpret_cast<const bf16x8*>(Wload + (c + 4) * 64 + j * 8);
            abuf[d][0] = *reinterpret_cast<const float4*>(Aload + (c + 4) * 64);
            abuf[d][1] = *reinterpret_cast<const float4*>(Aload + (c + 4) * 64 + 4);
        }
        __syncthreads();
        #pragma unroll
        for (int kk = 0; kk < 2; kk++) {
            bf16x8 af = *reinterpret_cast<const bf16x8*>(&Alds[arow][kk * 32 + g * 8]);
            #pragma unroll
            for (int n = 0; n < 4; n++) {
                bf16x8 wf = *reinterpret_cast<const bf16x8*>(
                    &Wlds[wbase + n * 16 + c16][kk * 32 + g * 8]);
                acc[n] = __builtin_amdgcn_mfma_f32_16x16x32_bf16(af, wf, acc[n], 0, 0, 0);
            }
        }
        __syncthreads();
    }

    const int row0 = i0 + (w >> 1) * 16 + g * 4;
    if (mat < 2) {
        float* outp = Pqk + ((size_t)(mat * 2 + s) * SEQ) * DH;
        #pragma unroll
        for (int n = 0; n < 4; n++) {
            int col = wbase + n * 16 + c16;
            float b0 = (s == 0) ? bias[col] : 0.f;
            #pragma unroll
            for (int r = 0; r < 4; r++)
                outp[(size_t)(row0 + r) * DH + col] = acc[n][r] + b0;
        }
    } else {
        float* outp = Pv + (size_t)s * DH * SEQ;
        #pragma unroll
        for (int n = 0; n < 4; n++) {
            int col = wbase + n * 16 + c16;
            float b0 = (s == 0) ? bias[col] : 0.f;
            float4 f = { acc[n][0] + b0, acc[n][1] + b0, acc[n][2] + b0, acc[n][3] + b0 };
            *reinterpret_cast<float4*>(&outp[(size_t)col * SEQ + row0]) = f;
        }
    }
}

// ---------------- Combine split-K partials -> bf16 Q, K, Vt. grid 1536, block 256.
__global__ __launch_bounds__(256) void combine_kernel(
    const float* __restrict__ Pqk, const float* __restrict__ Pv,
    short* __restrict__ Qws, short* __restrict__ Kws, short* __restrict__ Vtws)
{
    const int b = blockIdx.x;
    if (b < 1024) {
        int tid = b * 256 + threadIdx.x;
        int mat = tid >> 17;
        int idx4 = (tid & 131071) * 4;
        const float* p0 = Pqk + ((size_t)(mat * 2 + 0) * SEQ) * DH;
        const float* p1 = Pqk + ((size_t)(mat * 2 + 1) * SEQ) * DH;
        float4 a = *reinterpret_cast<const float4*>(p0 + idx4);
        float4 c = *reinterpret_cast<const float4*>(p1 + idx4);
        short4v o = { f2bf(a.x + c.x), f2bf(a.y + c.y), f2bf(a.z + c.z), f2bf(a.w + c.w) };
        short* outp = (mat == 0) ? Qws : Kws;
        *reinterpret_cast<short4v*>(outp + idx4) = o;
    } else {
        int tid = (b - 1024) * 256 + threadIdx.x;
        int idx4 = tid * 4;
        float4 a = *reinterpret_cast<const float4*>(Pv + idx4);
        float4 c = *reinterpret_cast<const float4*>(Pv + (size_t)DH * SEQ + idx4);
        short4v o = { f2bf(a.x + c.x), f2bf(a.y + c.y), f2bf(a.z + c.z), f2bf(a.w + c.w) };
        *reinterpret_cast<short4v*>(Vtws + idx4) = o;
    }
}

// ---------------- Flash attention, 16-way key split, 4 splits per block.
// grid (256, 4), block 256 (4 waves). Wave w handles split h = blockIdx.y*4 + w
// of q-tile blockIdx.x. Waves are fully independent (no __syncthreads).
__global__ __launch_bounds__(256) void flash_kernel(
    const short* __restrict__ Qws, const short* __restrict__ Kws, const short* __restrict__ Vtws,
    float* __restrict__ Opart, float* __restrict__ mpart, float* __restrict__ lpart)
{
    const int i  = blockIdx.x;
    const int w  = threadIdx.x >> 6;
    const int h  = blockIdx.y * 4 + w;
    const int NS = gridDim.y * 4;
    const int i0 = i * 16;
    const int lane = threadIdx.x & 63;
    const int g = lane >> 4, c16 = lane & 15;

    __shared__ short Slds[4][16][72];   // per-wave slice

    bf16x8 qf[4];
    #pragma unroll
    for (int kk = 0; kk < 4; kk++)
        qf[kk] = *reinterpret_cast<const bf16x8*>(Qws + (size_t)(i0 + c16) * DH + kk * 32 + g * 8);

    float m[4], lsum[4];
    f32x4 O[8];
    #pragma unroll
    for (int r = 0; r < 4; r++) { m[r] = -__builtin_inff(); lsum[r] = 0.f; }
    #pragma unroll
    for (int c = 0; c < 8; c++) O[c] = (f32x4){0.f, 0.f, 0.f, 0.f};

    const int njt = i / 4 + 1;
    const float C = 0.03188448666f;            // log2(e)/sqrt(2048)

    for (int jt = h; jt < njt; jt += NS) {
        const int j0 = jt * 64;
        f32x4 S[4];
        #pragma unroll
        for (int t = 0; t < 4; t++) S[t] = (f32x4){0.f, 0.f, 0.f, 0.f};
        #pragma unroll
        for (int kk = 0; kk < 4; kk++) {
            #pragma unroll
            for (int t = 0; t < 4; t++) {
                bf16x8 kf = *reinterpret_cast<const bf16x8*>(
                    Kws + (size_t)(j0 + t * 16 + c16) * DH + kk * 32 + g * 8);
                S[t] = __builtin_amdgcn_mfma_f32_16x16x32_bf16(qf[kk], kf, S[t], 0, 0, 0);
            }
        }
        float s2[4][4];
        #pragma unroll
        for (int t = 0; t < 4; t++) {
            int key = j0 + t * 16 + c16;
            #pragma unroll
            for (int r = 0; r < 4; r++) {
                int q = i0 + g * 4 + r;
                s2[t][r] = (key > q) ? -__builtin_inff() : S[t][r] * C;
            }
        }
        float mnew[4], alpha[4];
        #pragma unroll
        for (int r = 0; r < 4; r++) {
            float rm = fmaxf(fmaxf(s2[0][r], s2[1][r]), fmaxf(s2[2][r], s2[3][r]));
            rm = fmaxf(rm, __shfl_xor(rm, 1));
            rm = fmaxf(rm, __shfl_xor(rm, 2));
            rm = fmaxf(rm, __shfl_xor(rm, 4));
            rm = fmaxf(rm, __shfl_xor(rm, 8));
            mnew[r] = fmaxf(m[r], rm);
            alpha[r] = fexp2(m[r] - mnew[r]);
            m[r] = mnew[r];
        }
        #pragma unroll
        for (int r = 0; r < 4; r++) {
            float ps = 0.f;
            #pragma unroll
            for (int t = 0; t < 4; t++) {
                float p = fexp2(s2[t][r] - mnew[r]);
                ps += p;
                Slds[w][g * 4 + r][t * 16 + c16] = f2bf(p);
            }
            ps += __shfl_xor(ps, 1);
            ps += __shfl_xor(ps, 2);
            ps += __shfl_xor(ps, 4);
            ps += __shfl_xor(ps, 8);
            lsum[r] = lsum[r] * alpha[r] + ps;
            #pragma unroll
            for (int c = 0; c < 8; c++) O[c][r] *= alpha[r];
        }
        #pragma unroll
        for (int kk2 = 0; kk2 < 2; kk2++) {
            bf16x8 pf = *reinterpret_cast<const bf16x8*>(&Slds[w][c16][kk2 * 32 + g * 8]);
            #pragma unroll
            for (int c = 0; c < 8; c++) {
                bf16x8 vf = *reinterpret_cast<const bf16x8*>(
                    Vtws + (size_t)(c * 16 + c16) * SEQ + j0 + kk2 * 32 + g * 8);
                O[c] = __builtin_amdgcn_mfma_f32_16x16x32_bf16(pf, vf, O[c], 0, 0, 0);
            }
        }
    }
    #pragma unroll
    for (int c = 0; c < 8; c++) {
        int col = c * 16 + c16;
        #pragma unroll
        for (int r = 0; r < 4; r++)
            Opart[((size_t)h * SEQ + i0 + g * 4 + r) * DH + col] = O[c][r];
    }
    if (c16 == 0) {
        #pragma unroll
        for (int r = 0; r < 4; r++) {
            mpart[h * SEQ + i0 + g * 4 + r] = m[r];
            lpart[h * SEQ + i0 + g * 4 + r] = lsum[r];
        }
    }
}

// ---------------- Merge NS split partials. grid 2048, block 256 (2 rows/block).
__global__ __launch_bounds__(256) void merge_kernel(
    const float* __restrict__ Opart, const float* __restrict__ mpart, const float* __restrict__ lpart,
    float* __restrict__ out, int NS)
{
    const int row = blockIdx.x * 2 + (threadIdx.x >> 7);
    const int col = threadIdx.x & 127;
    float mh[16];
    float M = -__builtin_inff();
    for (int hh = 0; hh < NS; hh++) {
        mh[hh] = mpart[hh * SEQ + row];
        M = fmaxf(M, mh[hh]);
    }
    float denom = 0.f, num = 0.f;
    for (int hh = 0; hh < NS; hh++) {
        float wgt = fexp2(mh[hh] - M);
        denom += lpart[hh * SEQ + row] * wgt;
        num   += Opart[((size_t)hh * SEQ + row) * DH + col] * wgt;
    }
    out[(size_t)row * DH + col] = num / denom;
}

extern "C" void kernel_launch(void* const* d_in, const int* in_sizes, int n_in,
                              void* d_out, int out_size, void* d_ws, size_t ws_size,
                              hipStream_t stream) {
    const float* inq = (const float*)d_in[0];
    const float* ink = (const float*)d_in[1];
    const float* inv = (const float*)d_in[2];
    const float* wq  = (const float*)d_in[3];
    const float* bq  = (const float*)d_in[4];
    const float* wk  = (const float*)d_in[5];
    const float* bk  = (const float*)d_in[6];
    const float* wv  = (const float*)d_in[7];
    const float* bv  = (const float*)d_in[8];

    const int NS = 16;

    char* ws = (char*)d_ws;
    short* Qws   = (short*)(ws);                         // [0, 1 MB)
    short* Kws   = (short*)(ws + (1u << 20));            // [1, 2 MB)
    short* Vtws  = (short*)(ws + (2u << 20));            // [2, 3 MB)  ([128][4096])
    short* Wbf   = (short*)(ws + (3u << 20));            // [3, 4.5 MB) bf16 W (proj-only)
    float* Pqk   = (float*)(ws + 4718592);               // [4.5, 12.5 MB)
    float* Pv    = (float*)(ws + 13107200);              // [12.5, 16.5 MB)
    float* Opart = (float*)(ws + (3u << 20));            // aliases Wbf/Pqk/Pv (dead by flash)
    float* mpart = (float*)(ws + (3u << 20) + (size_t)NS * SEQ * DH * 4);
    float* lpart = mpart + (size_t)NS * SEQ;

    convw_kernel<<<768, 256, 0, stream>>>(wq, wk, wv, Wbf);
    proj_kernel<<<dim3(128, 3, 2), 256, 0, stream>>>(inq, ink, inv, Wbf, bq, bk, bv, Pqk, Pv);
    combine_kernel<<<1536, 256, 0, stream>>>(Pqk, Pv, Qws, Kws, Vtws);
    flash_kernel<<<dim3(256, 4), 256, 0, stream>>>(Qws, Kws, Vtws, Opart, mpart, lpart);
    merge_kernel<<<2048, 256, 0, stream>>>(Opart, mpart, lpart, (float*)d_out, NS);
}

// Round 7
// 188.464 us; speedup vs baseline: 1.1782x; 1.1782x over previous
//
#include <hip/hip_runtime.h>

#define SEQ 4096
#define DM  2048
#define DH  128
#define NSPLIT 8

typedef __attribute__((ext_vector_type(8))) short bf16x8;
typedef __attribute__((ext_vector_type(4))) short short4v;
typedef __attribute__((ext_vector_type(4))) float f32x4;

__device__ inline short f2bf(float f) {
    union { float f; unsigned u; } x; x.f = f;
    unsigned r = x.u + 0x7fffu + ((x.u >> 16) & 1u);
    return (short)(r >> 16);
}

__device__ inline float fexp2(float f) { return __builtin_amdgcn_exp2f(f); }

// ---------------- W fp32 -> bf16 pre-convert. grid 768, block 256. Wbf[3][128][2048]
__global__ __launch_bounds__(256) void convw_kernel(
    const float* __restrict__ wq, const float* __restrict__ wk, const float* __restrict__ wv,
    short* __restrict__ Wbf)
{
    int idx = blockIdx.x * 256 + threadIdx.x;
    int mat = idx >> 16;
    int off = (idx & 65535) * 4;
    const float* W = (mat == 0) ? wq : (mat == 1) ? wk : wv;
    float4 v = *reinterpret_cast<const float4*>(W + off);
    short4v s = { f2bf(v.x), f2bf(v.y), f2bf(v.z), f2bf(v.w) };
    *reinterpret_cast<short4v*>(Wbf + (size_t)mat * DH * DM + off) = s;
}

// ---------------- Projection, split-K x2. grid (128, 3, 2), block 256 (4 waves).
// (unchanged from round 5 — depth-4 register prefetch, LDS-staged A and W)
__global__ __launch_bounds__(256) void proj_kernel(
    const float* __restrict__ inq, const float* __restrict__ ink, const float* __restrict__ inv,
    const short* __restrict__ Wbf,
    const float* __restrict__ bq, const float* __restrict__ bk, const float* __restrict__ bv,
    float* __restrict__ Pqk, float* __restrict__ Pv)
{
    const int mat = blockIdx.y;
    const int s   = blockIdx.z;
    const float* A    = (mat == 0) ? inq : (mat == 1) ? ink : inv;
    const float* bias = (mat == 0) ? bq : (mat == 1) ? bk : bv;

    const int tid  = threadIdx.x;
    const int lane = tid & 63;
    const int w    = tid >> 6;
    const int g    = lane >> 4;
    const int c16  = lane & 15;
    const int i0   = blockIdx.x * 32;
    const int kb   = s * 1024;

    __shared__ short Alds[32][72];
    __shared__ short Wlds[128][72];

    const int ar = tid >> 3, ac = (tid & 7) * 8;
    const float* Aload = A + (size_t)(i0 + ar) * DM + kb + ac;
    const int wr = tid >> 1, wc = (tid & 1) * 32;
    const short* Wload = Wbf + (size_t)mat * DH * DM + (size_t)wr * DM + kb + wc;

    f32x4 acc[4];
    #pragma unroll
    for (int n = 0; n < 4; n++) acc[n] = (f32x4){0.f, 0.f, 0.f, 0.f};

    float4  abuf[4][2];
    bf16x8  wbuf[4][4];

    #pragma unroll
    for (int d = 0; d < 4; d++) {
        #pragma unroll
        for (int j = 0; j < 4; j++)
            wbuf[d][j] = *reinterpret_cast<const bf16x8*>(Wload + d * 64 + j * 8);
        abuf[d][0] = *reinterpret_cast<const float4*>(Aload + d * 64);
        abuf[d][1] = *reinterpret_cast<const float4*>(Aload + d * 64 + 4);
    }

    const int arow = (w >> 1) * 16 + c16;
    const int wbase = (w & 1) * 64;

    #pragma unroll
    for (int c = 0; c < 16; c++) {
        const int d = c & 3;
        {
            short4v s0 = { f2bf(abuf[d][0].x), f2bf(abuf[d][0].y),
                           f2bf(abuf[d][0].z), f2bf(abuf[d][0].w) };
            short4v s1 = { f2bf(abuf[d][1].x), f2bf(abuf[d][1].y),
                           f2bf(abuf[d][1].z), f2bf(abuf[d][1].w) };
            *reinterpret_cast<short4v*>(&Alds[ar][ac])     = s0;
            *reinterpret_cast<short4v*>(&Alds[ar][ac + 4]) = s1;
            #pragma unroll
            for (int j = 0; j < 4; j++)
                *reinterpret_cast<bf16x8*>(&Wlds[wr][wc + j * 8]) = wbuf[d][j];
        }
        if (c + 4 < 16) {
            #pragma unroll
            for (int j = 0; j < 4; j++)
                wbuf[d][j] = *reinterpret_cast<const bf16x8*>(Wload + (c + 4) * 64 + j * 8);
            abuf[d][0] = *reinterpret_cast<const float4*>(Aload + (c + 4) * 64);
            abuf[d][1] = *reinterpret_cast<const float4*>(Aload + (c + 4) * 64 + 4);
        }
        __syncthreads();
        #pragma unroll
        for (int kk = 0; kk < 2; kk++) {
            bf16x8 af = *reinterpret_cast<const bf16x8*>(&Alds[arow][kk * 32 + g * 8]);
            #pragma unroll
            for (int n = 0; n < 4; n++) {
                bf16x8 wf = *reinterpret_cast<const bf16x8*>(
                    &Wlds[wbase + n * 16 + c16][kk * 32 + g * 8]);
                acc[n] = __builtin_amdgcn_mfma_f32_16x16x32_bf16(af, wf, acc[n], 0, 0, 0);
            }
        }
        __syncthreads();
    }

    const int row0 = i0 + (w >> 1) * 16 + g * 4;
    if (mat < 2) {
        float* outp = Pqk + ((size_t)(mat * 2 + s) * SEQ) * DH;
        #pragma unroll
        for (int n = 0; n < 4; n++) {
            int col = wbase + n * 16 + c16;
            float b0 = (s == 0) ? bias[col] : 0.f;
            #pragma unroll
            for (int r = 0; r < 4; r++)
                outp[(size_t)(row0 + r) * DH + col] = acc[n][r] + b0;
        }
    } else {
        float* outp = Pv + (size_t)s * DH * SEQ;
        #pragma unroll
        for (int n = 0; n < 4; n++) {
            int col = wbase + n * 16 + c16;
            float b0 = (s == 0) ? bias[col] : 0.f;
            float4 f = { acc[n][0] + b0, acc[n][1] + b0, acc[n][2] + b0, acc[n][3] + b0 };
            *reinterpret_cast<float4*>(&outp[(size_t)col * SEQ + row0]) = f;
        }
    }
}

// ---------------- Combine split-K partials -> bf16 Q, K, Vt. grid 1536, block 256.
__global__ __launch_bounds__(256) void combine_kernel(
    const float* __restrict__ Pqk, const float* __restrict__ Pv,
    short* __restrict__ Qws, short* __restrict__ Kws, short* __restrict__ Vtws)
{
    const int b = blockIdx.x;
    if (b < 1024) {
        int tid = b * 256 + threadIdx.x;
        int mat = tid >> 17;
        int idx4 = (tid & 131071) * 4;
        const float* p0 = Pqk + ((size_t)(mat * 2 + 0) * SEQ) * DH;
        const float* p1 = Pqk + ((size_t)(mat * 2 + 1) * SEQ) * DH;
        float4 a = *reinterpret_cast<const float4*>(p0 + idx4);
        float4 c = *reinterpret_cast<const float4*>(p1 + idx4);
        short4v o = { f2bf(a.x + c.x), f2bf(a.y + c.y), f2bf(a.z + c.z), f2bf(a.w + c.w) };
        short* outp = (mat == 0) ? Qws : Kws;
        *reinterpret_cast<short4v*>(outp + idx4) = o;
    } else {
        int tid = (b - 1024) * 256 + threadIdx.x;
        int idx4 = tid * 4;
        float4 a = *reinterpret_cast<const float4*>(Pv + idx4);
        float4 c = *reinterpret_cast<const float4*>(Pv + (size_t)DH * SEQ + idx4);
        short4v o = { f2bf(a.x + c.x), f2bf(a.y + c.y), f2bf(a.z + c.z), f2bf(a.w + c.w) };
        *reinterpret_cast<short4v*>(Vtws + idx4) = o;
    }
}

// ---------------- Flash attention, block-cooperative K/V staging.
// grid (64, NSPLIT), block 256 (4 waves). Block covers 64 q-rows (wave w:
// rows qb*64+16w..+15); all waves share LDS-staged K-tile/V-tile (64 keys),
// depth-1 register prefetch of the next tile. Split y handles jt = y, y+NS,...
__global__ __launch_bounds__(256) void flash_kernel(
    const short* __restrict__ Qws, const short* __restrict__ Kws, const short* __restrict__ Vtws,
    float* __restrict__ Opart, float* __restrict__ mpart, float* __restrict__ lpart)
{
    const int qb = blockIdx.x;
    const int y  = blockIdx.y;
    const int tid = threadIdx.x;
    const int w    = tid >> 6;
    const int lane = tid & 63;
    const int g = lane >> 4, c16 = lane & 15;
    const int i0 = qb * 64 + w * 16;     // this wave's q-strip

    __shared__ short Klds[64][136];      // [key][dim], pad 8
    __shared__ short Vlds[128][72];      // [dim][key], pad 8
    __shared__ short Slds[4][16][72];    // per-wave P round-trip

    // staging assignments (256 threads, 64B each)
    const int kkey = tid >> 2,  kdim = (tid & 3) * 32;
    const int vdim = tid >> 1,  vkey = (tid & 1) * 32;

    bf16x8 kreg[4], vreg[4];

    bf16x8 qf[4];
    #pragma unroll
    for (int kk = 0; kk < 4; kk++)
        qf[kk] = *reinterpret_cast<const bf16x8*>(Qws + (size_t)(i0 + c16) * DH + kk * 32 + g * 8);

    float m[4], lsum[4];
    f32x4 O[8];
    #pragma unroll
    for (int r = 0; r < 4; r++) { m[r] = -__builtin_inff(); lsum[r] = 0.f; }
    #pragma unroll
    for (int c = 0; c < 8; c++) O[c] = (f32x4){0.f, 0.f, 0.f, 0.f};

    const float C = 0.03188448666f;      // log2(e)/sqrt(2048)

    if (qb >= y) {
        // prologue: stage first tile
        {
            const int j0 = y * 64;
            #pragma unroll
            for (int j = 0; j < 4; j++) {
                kreg[j] = *reinterpret_cast<const bf16x8*>(
                    Kws + (size_t)(j0 + kkey) * DH + kdim + j * 8);
                vreg[j] = *reinterpret_cast<const bf16x8*>(
                    Vtws + (size_t)vdim * SEQ + j0 + vkey + j * 8);
            }
            #pragma unroll
            for (int j = 0; j < 4; j++) {
                *reinterpret_cast<bf16x8*>(&Klds[kkey][kdim + j * 8]) = kreg[j];
                *reinterpret_cast<bf16x8*>(&Vlds[vdim][vkey + j * 8]) = vreg[j];
            }
        }
        __syncthreads();

        for (int jt = y; jt <= qb; jt += NSPLIT) {
            const bool more = (jt + NSPLIT <= qb);
            if (more) {
                const int jn = (jt + NSPLIT) * 64;
                #pragma unroll
                for (int j = 0; j < 4; j++) {
                    kreg[j] = *reinterpret_cast<const bf16x8*>(
                        Kws + (size_t)(jn + kkey) * DH + kdim + j * 8);
                    vreg[j] = *reinterpret_cast<const bf16x8*>(
                        Vtws + (size_t)vdim * SEQ + jn + vkey + j * 8);
                }
            }
            const int j0 = jt * 64;
            // ---- QK^T from LDS
            f32x4 S[4];
            #pragma unroll
            for (int t = 0; t < 4; t++) S[t] = (f32x4){0.f, 0.f, 0.f, 0.f};
            #pragma unroll
            for (int kk = 0; kk < 4; kk++) {
                #pragma unroll
                for (int t = 0; t < 4; t++) {
                    bf16x8 kf = *reinterpret_cast<const bf16x8*>(
                        &Klds[t * 16 + c16][kk * 32 + g * 8]);
                    S[t] = __builtin_amdgcn_mfma_f32_16x16x32_bf16(qf[kk], kf, S[t], 0, 0, 0);
                }
            }
            // ---- mask + scale
            float s2[4][4];
            #pragma unroll
            for (int t = 0; t < 4; t++) {
                int key = j0 + t * 16 + c16;
                #pragma unroll
                for (int r = 0; r < 4; r++) {
                    int q = i0 + g * 4 + r;
                    s2[t][r] = (key > q) ? -__builtin_inff() : S[t][r] * C;
                }
            }
            // ---- online softmax
            float mnew[4], alpha[4];
            #pragma unroll
            for (int r = 0; r < 4; r++) {
                float rm = fmaxf(fmaxf(s2[0][r], s2[1][r]), fmaxf(s2[2][r], s2[3][r]));
                rm = fmaxf(rm, __shfl_xor(rm, 1));
                rm = fmaxf(rm, __shfl_xor(rm, 2));
                rm = fmaxf(rm, __shfl_xor(rm, 4));
                rm = fmaxf(rm, __shfl_xor(rm, 8));
                mnew[r] = fmaxf(m[r], rm);
                alpha[r] = fexp2(m[r] - mnew[r]);
                m[r] = mnew[r];
            }
            #pragma unroll
            for (int r = 0; r < 4; r++) {
                float ps = 0.f;
                #pragma unroll
                for (int t = 0; t < 4; t++) {
                    float p = fexp2(s2[t][r] - mnew[r]);
                    ps += p;
                    Slds[w][g * 4 + r][t * 16 + c16] = f2bf(p);
                }
                ps += __shfl_xor(ps, 1);
                ps += __shfl_xor(ps, 2);
                ps += __shfl_xor(ps, 4);
                ps += __shfl_xor(ps, 8);
                lsum[r] = lsum[r] * alpha[r] + ps;
                #pragma unroll
                for (int c = 0; c < 8; c++) O[c][r] *= alpha[r];
            }
            // ---- P V from LDS
            #pragma unroll
            for (int kk2 = 0; kk2 < 2; kk2++) {
                bf16x8 pf = *reinterpret_cast<const bf16x8*>(&Slds[w][c16][kk2 * 32 + g * 8]);
                #pragma unroll
                for (int c = 0; c < 8; c++) {
                    bf16x8 vf = *reinterpret_cast<const bf16x8*>(
                        &Vlds[c * 16 + c16][kk2 * 32 + g * 8]);
                    O[c] = __builtin_amdgcn_mfma_f32_16x16x32_bf16(pf, vf, O[c], 0, 0, 0);
                }
            }
            __syncthreads();             // everyone done reading Klds/Vlds
            if (more) {
                #pragma unroll
                for (int j = 0; j < 4; j++) {
                    *reinterpret_cast<bf16x8*>(&Klds[kkey][kdim + j * 8]) = kreg[j];
                    *reinterpret_cast<bf16x8*>(&Vlds[vdim][vkey + j * 8]) = vreg[j];
                }
                __syncthreads();
            }
        }
        // ---- write partials (O only when this block had tiles)
        #pragma unroll
        for (int c = 0; c < 8; c++) {
            int col = c * 16 + c16;
            #pragma unroll
            for (int r = 0; r < 4; r++)
                Opart[((size_t)y * SEQ + i0 + g * 4 + r) * DH + col] = O[c][r];
        }
    }
    if (c16 == 0) {
        #pragma unroll
        for (int r = 0; r < 4; r++) {
            mpart[y * SEQ + i0 + g * 4 + r] = m[r];
            lpart[y * SEQ + i0 + g * 4 + r] = lsum[r];
        }
    }
}

// ---------------- Merge NS split partials. grid 2048, block 256 (2 rows/block).
__global__ __launch_bounds__(256) void merge_kernel(
    const float* __restrict__ Opart, const float* __restrict__ mpart, const float* __restrict__ lpart,
    float* __restrict__ out, int NS)
{
    const int row = blockIdx.x * 2 + (threadIdx.x >> 7);
    const int col = threadIdx.x & 127;
    float mh[16];
    float M = -__builtin_inff();
    for (int hh = 0; hh < NS; hh++) {
        mh[hh] = mpart[hh * SEQ + row];
        M = fmaxf(M, mh[hh]);
    }
    float denom = 0.f, num = 0.f;
    for (int hh = 0; hh < NS; hh++) {
        float wgt = fexp2(mh[hh] - M);          // -inf -> 0 (0*poison stays finite)
        denom += lpart[hh * SEQ + row] * wgt;
        num   += Opart[((size_t)hh * SEQ + row) * DH + col] * wgt;
    }
    out[(size_t)row * DH + col] = num / denom;
}

extern "C" void kernel_launch(void* const* d_in, const int* in_sizes, int n_in,
                              void* d_out, int out_size, void* d_ws, size_t ws_size,
                              hipStream_t stream) {
    const float* inq = (const float*)d_in[0];
    const float* ink = (const float*)d_in[1];
    const float* inv = (const float*)d_in[2];
    const float* wq  = (const float*)d_in[3];
    const float* bq  = (const float*)d_in[4];
    const float* wk  = (const float*)d_in[5];
    const float* bk  = (const float*)d_in[6];
    const float* wv  = (const float*)d_in[7];
    const float* bv  = (const float*)d_in[8];

    char* ws = (char*)d_ws;
    short* Qws   = (short*)(ws);                         // [0, 1 MB)
    short* Kws   = (short*)(ws + (1u << 20));            // [1, 2 MB)
    short* Vtws  = (short*)(ws + (2u << 20));            // [2, 3 MB)  ([128][4096])
    short* Wbf   = (short*)(ws + (3u << 20));            // [3, 4.5 MB) bf16 W (proj-only)
    float* Pqk   = (float*)(ws + 4718592);               // [4.5, 12.5 MB)
    float* Pv    = (float*)(ws + 13107200);              // [12.5, 16.5 MB)
    float* Opart = (float*)(ws + (3u << 20));            // aliases Wbf/Pqk/Pv (dead by flash)
    float* mpart = (float*)(ws + (3u << 20) + (size_t)NSPLIT * SEQ * DH * 4);
    float* lpart = mpart + (size_t)NSPLIT * SEQ;

    convw_kernel<<<768, 256, 0, stream>>>(wq, wk, wv, Wbf);
    proj_kernel<<<dim3(128, 3, 2), 256, 0, stream>>>(inq, ink, inv, Wbf, bq, bk, bv, Pqk, Pv);
    combine_kernel<<<1536, 256, 0, stream>>>(Pqk, Pv, Qws, Kws, Vtws);
    flash_kernel<<<dim3(64, NSPLIT), 256, 0, stream>>>(Qws, Kws, Vtws, Opart, mpart, lpart);
    merge_kernel<<<2048, 256, 0, stream>>>(Opart, mpart, lpart, (float*)d_out, NSPLIT);
}

// Round 8
// 184.826 us; speedup vs baseline: 1.2014x; 1.0197x over previous
//
#include <hip/hip_runtime.h>

#define SEQ 4096
#define DM  2048
#define DH  128
#define NSPLIT 8

typedef __attribute__((ext_vector_type(8))) short bf16x8;
typedef __attribute__((ext_vector_type(4))) short short4v;
typedef __attribute__((ext_vector_type(4))) float f32x4;

__device__ inline short f2bf(float f) {
    union { float f; unsigned u; } x; x.f = f;
    unsigned r = x.u + 0x7fffu + ((x.u >> 16) & 1u);
    return (short)(r >> 16);
}

__device__ inline float fexp2(float f) { return __builtin_amdgcn_exp2f(f); }

// ---------------- W fp32 -> bf16 pre-convert. grid 768, block 256. Wbf[3][128][2048]
__global__ __launch_bounds__(256) void convw_kernel(
    const float* __restrict__ wq, const float* __restrict__ wk, const float* __restrict__ wv,
    short* __restrict__ Wbf)
{
    int idx = blockIdx.x * 256 + threadIdx.x;
    int mat = idx >> 16;
    int off = (idx & 65535) * 4;
    const float* W = (mat == 0) ? wq : (mat == 1) ? wk : wv;
    float4 v = *reinterpret_cast<const float4*>(W + off);
    short4v s = { f2bf(v.x), f2bf(v.y), f2bf(v.z), f2bf(v.w) };
    *reinterpret_cast<short4v*>(Wbf + (size_t)mat * DH * DM + off) = s;
}

// ---------------- Projection, split-K x4. grid (64, 3, 4), block 256 (4 waves).
// Block tile: 64 rows x 128 cols, K-range 512, BK=64 (8 chunks).
// Wave w = (row-half w>>1 [32 rows], col-half w&1 [64 cols]): 16 MFMA per chunk
// against 12 ds_read_b128. A: depth-4 register prefetch (HBM); W: depth-2 (L2).
// Issue W before A each iter so LDS-write waits drain only old loads.
__global__ __launch_bounds__(256) void proj_kernel(
    const float* __restrict__ inq, const float* __restrict__ ink, const float* __restrict__ inv,
    const short* __restrict__ Wbf,
    float* __restrict__ Pqk, float* __restrict__ Pv)
{
    const int mat = blockIdx.y;
    const int s   = blockIdx.z;
    const float* A = (mat == 0) ? inq : (mat == 1) ? ink : inv;

    const int tid  = threadIdx.x;
    const int lane = tid & 63;
    const int w    = tid >> 6;
    const int g    = lane >> 4;
    const int c16  = lane & 15;
    const int i0   = blockIdx.x * 64;
    const int kb   = s * 512;

    __shared__ short Alds[64][72];    // 64 rows x 64 k bf16, stride 144B (16B-mult)
    __shared__ short Wlds[128][72];

    // A stager: thread t -> row t>>2 (0..63), cols (t&3)*16 floats (4 float4 = 64B)
    const int ar = tid >> 2, ac = (tid & 3) * 16;
    const float* Aload = A + (size_t)(i0 + ar) * DM + kb + ac;
    // W stager: thread t -> row t>>1 (0..127), cols (t&1)*32 bf16 (4 bf16x8 = 64B)
    const int wr = tid >> 1, wc = (tid & 1) * 32;
    const short* Wload = Wbf + (size_t)mat * DH * DM + (size_t)wr * DM + kb + wc;

    f32x4 acc[2][4];
    #pragma unroll
    for (int mI = 0; mI < 2; mI++)
        #pragma unroll
        for (int n = 0; n < 4; n++) acc[mI][n] = (f32x4){0.f, 0.f, 0.f, 0.f};

    float4  abuf[4][4];   // depth 4
    bf16x8  wbuf[2][4];   // depth 2

    // prologue: W chunks 0..1, A chunks 0..3 (interleaved W-first per chunk)
    #pragma unroll
    for (int d = 0; d < 2; d++) {
        #pragma unroll
        for (int j = 0; j < 4; j++)
            wbuf[d][j] = *reinterpret_cast<const bf16x8*>(Wload + d * 64 + j * 8);
        #pragma unroll
        for (int j = 0; j < 4; j++)
            abuf[d][j] = *reinterpret_cast<const float4*>(Aload + d * 64 + j * 4);
    }
    #pragma unroll
    for (int d = 2; d < 4; d++)
        #pragma unroll
        for (int j = 0; j < 4; j++)
            abuf[d][j] = *reinterpret_cast<const float4*>(Aload + d * 64 + j * 4);

    const int rw = (w >> 1) * 32;     // wave's row base within tile
    const int cw = (w & 1) * 64;      // wave's col base

    #pragma unroll
    for (int c = 0; c < 8; c++) {
        const int da = c & 3, dw = c & 1;
        // LDS-write chunk c (waits: W issued 2 iters ago, A 4 iters ago)
        {
            #pragma unroll
            for (int j = 0; j < 4; j++)
                *reinterpret_cast<bf16x8*>(&Wlds[wr][wc + j * 8]) = wbuf[dw][j];
            #pragma unroll
            for (int j = 0; j < 2; j++) {
                float4 v0 = abuf[da][j * 2], v1 = abuf[da][j * 2 + 1];
                bf16x8 sv = { f2bf(v0.x), f2bf(v0.y), f2bf(v0.z), f2bf(v0.w),
                              f2bf(v1.x), f2bf(v1.y), f2bf(v1.z), f2bf(v1.w) };
                *reinterpret_cast<bf16x8*>(&Alds[ar][ac + j * 8]) = sv;
            }
        }
        // prefetch: W chunk c+2, then A chunk c+4
        if (c + 2 < 8) {
            #pragma unroll
            for (int j = 0; j < 4; j++)
                wbuf[dw][j] = *reinterpret_cast<const bf16x8*>(Wload + (c + 2) * 64 + j * 8);
        }
        if (c + 4 < 8) {
            #pragma unroll
            for (int j = 0; j < 4; j++)
                abuf[da][j] = *reinterpret_cast<const float4*>(Aload + (c + 4) * 64 + j * 4);
        }
        __syncthreads();
        #pragma unroll
        for (int kk = 0; kk < 2; kk++) {
            bf16x8 af0 = *reinterpret_cast<const bf16x8*>(&Alds[rw + c16][kk * 32 + g * 8]);
            bf16x8 af1 = *reinterpret_cast<const bf16x8*>(&Alds[rw + 16 + c16][kk * 32 + g * 8]);
            #pragma unroll
            for (int n = 0; n < 4; n++) {
                bf16x8 wf = *reinterpret_cast<const bf16x8*>(
                    &Wlds[cw + n * 16 + c16][kk * 32 + g * 8]);
                acc[0][n] = __builtin_amdgcn_mfma_f32_16x16x32_bf16(af0, wf, acc[0][n], 0, 0, 0);
                acc[1][n] = __builtin_amdgcn_mfma_f32_16x16x32_bf16(af1, wf, acc[1][n], 0, 0, 0);
            }
        }
        __syncthreads();
    }

    if (mat < 2) {
        float* outp = Pqk + ((size_t)(mat * 4 + s) * SEQ) * DH;
        #pragma unroll
        for (int mI = 0; mI < 2; mI++) {
            int row0 = i0 + rw + mI * 16 + g * 4;
            #pragma unroll
            for (int n = 0; n < 4; n++) {
                int col = cw + n * 16 + c16;
                #pragma unroll
                for (int r = 0; r < 4; r++)
                    outp[(size_t)(row0 + r) * DH + col] = acc[mI][n][r];
            }
        }
    } else {
        float* outp = Pv + (size_t)s * DH * SEQ;
        #pragma unroll
        for (int mI = 0; mI < 2; mI++) {
            int row0 = i0 + rw + mI * 16 + g * 4;
            #pragma unroll
            for (int n = 0; n < 4; n++) {
                int col = cw + n * 16 + c16;
                float4 f = { acc[mI][n][0], acc[mI][n][1], acc[mI][n][2], acc[mI][n][3] };
                *reinterpret_cast<float4*>(&outp[(size_t)col * SEQ + row0]) = f;
            }
        }
    }
}

// ---------------- Combine 4 split-K partials + bias -> bf16 Q, K, Vt. grid 1536.
__global__ __launch_bounds__(256) void combine_kernel(
    const float* __restrict__ Pqk, const float* __restrict__ Pv,
    const float* __restrict__ bq, const float* __restrict__ bk, const float* __restrict__ bv,
    short* __restrict__ Qws, short* __restrict__ Kws, short* __restrict__ Vtws)
{
    const int b = blockIdx.x;
    if (b < 1024) {
        int tid = b * 256 + threadIdx.x;          // 262144 threads, 4 elems each
        int mat = tid >> 17;
        int idx4 = (tid & 131071) * 4;
        float4 acc = {0.f, 0.f, 0.f, 0.f};
        #pragma unroll
        for (int s = 0; s < 4; s++) {
            float4 p = *reinterpret_cast<const float4*>(
                Pqk + ((size_t)(mat * 4 + s) * SEQ) * DH + idx4);
            acc.x += p.x; acc.y += p.y; acc.z += p.z; acc.w += p.w;
        }
        const float* bias = (mat == 0) ? bq : bk;
        int col = idx4 & (DH - 1);                // DH=128, float4-aligned
        acc.x += bias[col]; acc.y += bias[col + 1]; acc.z += bias[col + 2]; acc.w += bias[col + 3];
        short4v o = { f2bf(acc.x), f2bf(acc.y), f2bf(acc.z), f2bf(acc.w) };
        short* outp = (mat == 0) ? Qws : Kws;
        *reinterpret_cast<short4v*>(outp + idx4) = o;
    } else {
        int tid = (b - 1024) * 256 + threadIdx.x; // 131072 threads, 4 elems each
        int idx4 = tid * 4;
        float4 acc = {0.f, 0.f, 0.f, 0.f};
        #pragma unroll
        for (int s = 0; s < 4; s++) {
            float4 p = *reinterpret_cast<const float4*>(Pv + (size_t)s * DH * SEQ + idx4);
            acc.x += p.x; acc.y += p.y; acc.z += p.z; acc.w += p.w;
        }
        float bvv = bv[idx4 >> 12];               // row = idx4 / SEQ (SEQ=4096)
        acc.x += bvv; acc.y += bvv; acc.z += bvv; acc.w += bvv;
        short4v o = { f2bf(acc.x), f2bf(acc.y), f2bf(acc.z), f2bf(acc.w) };
        *reinterpret_cast<short4v*>(Vtws + idx4) = o;
    }
}

// ---------------- Flash attention, block-cooperative K/V staging. (round-7 proven)
// grid (64, NSPLIT), block 256 (4 waves).
__global__ __launch_bounds__(256) void flash_kernel(
    const short* __restrict__ Qws, const short* __restrict__ Kws, const short* __restrict__ Vtws,
    float* __restrict__ Opart, float* __restrict__ mpart, float* __restrict__ lpart)
{
    const int qb = blockIdx.x;
    const int y  = blockIdx.y;
    const int tid = threadIdx.x;
    const int w    = tid >> 6;
    const int lane = tid & 63;
    const int g = lane >> 4, c16 = lane & 15;
    const int i0 = qb * 64 + w * 16;

    __shared__ short Klds[64][136];
    __shared__ short Vlds[128][72];
    __shared__ short Slds[4][16][72];

    const int kkey = tid >> 2,  kdim = (tid & 3) * 32;
    const int vdim = tid >> 1,  vkey = (tid & 1) * 32;

    bf16x8 kreg[4], vreg[4];

    bf16x8 qf[4];
    #pragma unroll
    for (int kk = 0; kk < 4; kk++)
        qf[kk] = *reinterpret_cast<const bf16x8*>(Qws + (size_t)(i0 + c16) * DH + kk * 32 + g * 8);

    float m[4], lsum[4];
    f32x4 O[8];
    #pragma unroll
    for (int r = 0; r < 4; r++) { m[r] = -__builtin_inff(); lsum[r] = 0.f; }
    #pragma unroll
    for (int c = 0; c < 8; c++) O[c] = (f32x4){0.f, 0.f, 0.f, 0.f};

    const float C = 0.03188448666f;      // log2(e)/sqrt(2048)

    if (qb >= y) {
        {
            const int j0 = y * 64;
            #pragma unroll
            for (int j = 0; j < 4; j++) {
                kreg[j] = *reinterpret_cast<const bf16x8*>(
                    Kws + (size_t)(j0 + kkey) * DH + kdim + j * 8);
                vreg[j] = *reinterpret_cast<const bf16x8*>(
                    Vtws + (size_t)vdim * SEQ + j0 + vkey + j * 8);
            }
            #pragma unroll
            for (int j = 0; j < 4; j++) {
                *reinterpret_cast<bf16x8*>(&Klds[kkey][kdim + j * 8]) = kreg[j];
                *reinterpret_cast<bf16x8*>(&Vlds[vdim][vkey + j * 8]) = vreg[j];
            }
        }
        __syncthreads();

        for (int jt = y; jt <= qb; jt += NSPLIT) {
            const bool more = (jt + NSPLIT <= qb);
            if (more) {
                const int jn = (jt + NSPLIT) * 64;
                #pragma unroll
                for (int j = 0; j < 4; j++) {
                    kreg[j] = *reinterpret_cast<const bf16x8*>(
                        Kws + (size_t)(jn + kkey) * DH + kdim + j * 8);
                    vreg[j] = *reinterpret_cast<const bf16x8*>(
                        Vtws + (size_t)vdim * SEQ + jn + vkey + j * 8);
                }
            }
            const int j0 = jt * 64;
            f32x4 S[4];
            #pragma unroll
            for (int t = 0; t < 4; t++) S[t] = (f32x4){0.f, 0.f, 0.f, 0.f};
            #pragma unroll
            for (int kk = 0; kk < 4; kk++) {
                #pragma unroll
                for (int t = 0; t < 4; t++) {
                    bf16x8 kf = *reinterpret_cast<const bf16x8*>(
                        &Klds[t * 16 + c16][kk * 32 + g * 8]);
                    S[t] = __builtin_amdgcn_mfma_f32_16x16x32_bf16(qf[kk], kf, S[t], 0, 0, 0);
                }
            }
            float s2[4][4];
            #pragma unroll
            for (int t = 0; t < 4; t++) {
                int key = j0 + t * 16 + c16;
                #pragma unroll
                for (int r = 0; r < 4; r++) {
                    int q = i0 + g * 4 + r;
                    s2[t][r] = (key > q) ? -__builtin_inff() : S[t][r] * C;
                }
            }
            float mnew[4], alpha[4];
            #pragma unroll
            for (int r = 0; r < 4; r++) {
                float rm = fmaxf(fmaxf(s2[0][r], s2[1][r]), fmaxf(s2[2][r], s2[3][r]));
                rm = fmaxf(rm, __shfl_xor(rm, 1));
                rm = fmaxf(rm, __shfl_xor(rm, 2));
                rm = fmaxf(rm, __shfl_xor(rm, 4));
                rm = fmaxf(rm, __shfl_xor(rm, 8));
                mnew[r] = fmaxf(m[r], rm);
                alpha[r] = fexp2(m[r] - mnew[r]);
                m[r] = mnew[r];
            }
            #pragma unroll
            for (int r = 0; r < 4; r++) {
                float ps = 0.f;
                #pragma unroll
                for (int t = 0; t < 4; t++) {
                    float p = fexp2(s2[t][r] - mnew[r]);
                    ps += p;
                    Slds[w][g * 4 + r][t * 16 + c16] = f2bf(p);
                }
                ps += __shfl_xor(ps, 1);
                ps += __shfl_xor(ps, 2);
                ps += __shfl_xor(ps, 4);
                ps += __shfl_xor(ps, 8);
                lsum[r] = lsum[r] * alpha[r] + ps;
                #pragma unroll
                for (int c = 0; c < 8; c++) O[c][r] *= alpha[r];
            }
            #pragma unroll
            for (int kk2 = 0; kk2 < 2; kk2++) {
                bf16x8 pf = *reinterpret_cast<const bf16x8*>(&Slds[w][c16][kk2 * 32 + g * 8]);
                #pragma unroll
                for (int c = 0; c < 8; c++) {
                    bf16x8 vf = *reinterpret_cast<const bf16x8*>(
                        &Vlds[c * 16 + c16][kk2 * 32 + g * 8]);
                    O[c] = __builtin_amdgcn_mfma_f32_16x16x32_bf16(pf, vf, O[c], 0, 0, 0);
                }
            }
            __syncthreads();
            if (more) {
                #pragma unroll
                for (int j = 0; j < 4; j++) {
                    *reinterpret_cast<bf16x8*>(&Klds[kkey][kdim + j * 8]) = kreg[j];
                    *reinterpret_cast<bf16x8*>(&Vlds[vdim][vkey + j * 8]) = vreg[j];
                }
                __syncthreads();
            }
        }
        #pragma unroll
        for (int c = 0; c < 8; c++) {
            int col = c * 16 + c16;
            #pragma unroll
            for (int r = 0; r < 4; r++)
                Opart[((size_t)y * SEQ + i0 + g * 4 + r) * DH + col] = O[c][r];
        }
    }
    if (c16 == 0) {
        #pragma unroll
        for (int r = 0; r < 4; r++) {
            mpart[y * SEQ + i0 + g * 4 + r] = m[r];
            lpart[y * SEQ + i0 + g * 4 + r] = lsum[r];
        }
    }
}

// ---------------- Merge NS split partials. grid 2048, block 256 (2 rows/block).
__global__ __launch_bounds__(256) void merge_kernel(
    const float* __restrict__ Opart, const float* __restrict__ mpart, const float* __restrict__ lpart,
    float* __restrict__ out, int NS)
{
    const int row = blockIdx.x * 2 + (threadIdx.x >> 7);
    const int col = threadIdx.x & 127;
    float mh[16];
    float M = -__builtin_inff();
    for (int hh = 0; hh < NS; hh++) {
        mh[hh] = mpart[hh * SEQ + row];
        M = fmaxf(M, mh[hh]);
    }
    float denom = 0.f, num = 0.f;
    for (int hh = 0; hh < NS; hh++) {
        float wgt = fexp2(mh[hh] - M);
        denom += lpart[hh * SEQ + row] * wgt;
        num   += Opart[((size_t)hh * SEQ + row) * DH + col] * wgt;
    }
    out[(size_t)row * DH + col] = num / denom;
}

extern "C" void kernel_launch(void* const* d_in, const int* in_sizes, int n_in,
                              void* d_out, int out_size, void* d_ws, size_t ws_size,
                              hipStream_t stream) {
    const float* inq = (const float*)d_in[0];
    const float* ink = (const float*)d_in[1];
    const float* inv = (const float*)d_in[2];
    const float* wq  = (const float*)d_in[3];
    const float* bq  = (const float*)d_in[4];
    const float* wk  = (const float*)d_in[5];
    const float* bk  = (const float*)d_in[6];
    const float* wv  = (const float*)d_in[7];
    const float* bv  = (const float*)d_in[8];

    char* ws = (char*)d_ws;
    short* Qws   = (short*)(ws);                         // [0, 1 MB)
    short* Kws   = (short*)(ws + (1u << 20));            // [1, 2 MB)
    short* Vtws  = (short*)(ws + (2u << 20));            // [2, 3 MB)  ([128][4096])
    short* Wbf   = (short*)(ws + (3u << 20));            // [3, 4.5 MB) bf16 W (proj-only)
    float* Pqk   = (float*)(ws + 4718592);               // [4.5, 20.5 MB) [2 mat][4 s][4096][128]
    float* Pv    = (float*)(ws + 21495808);              // [20.5, 28.5 MB) [4 s][128][4096]
    float* Opart = (float*)(ws + (3u << 20));            // aliases Wbf/Pqk (dead by flash)
    float* mpart = (float*)(ws + (3u << 20) + (size_t)NSPLIT * SEQ * DH * 4);
    float* lpart = mpart + (size_t)NSPLIT * SEQ;

    convw_kernel<<<768, 256, 0, stream>>>(wq, wk, wv, Wbf);
    proj_kernel<<<dim3(64, 3, 4), 256, 0, stream>>>(inq, ink, inv, Wbf, Pqk, Pv);
    combine_kernel<<<1536, 256, 0, stream>>>(Pqk, Pv, bq, bk, bv, Qws, Kws, Vtws);
    flash_kernel<<<dim3(64, NSPLIT), 256, 0, stream>>>(Qws, Kws, Vtws, Opart, mpart, lpart);
    merge_kernel<<<2048, 256, 0, stream>>>(Opart, mpart, lpart, (float*)d_out, NSPLIT);
}

// Round 9
// 184.761 us; speedup vs baseline: 1.2018x; 1.0003x over previous
//
#include <hip/hip_runtime.h>

#define SEQ 4096
#define DM  2048
#define DH  128
#define NSPLIT 8

typedef __attribute__((ext_vector_type(8))) short bf16x8;
typedef __attribute__((ext_vector_type(4))) short short4v;
typedef __attribute__((ext_vector_type(4))) float f32x4;

__device__ inline short f2bf(float f) {
    union { float f; unsigned u; } x; x.f = f;
    unsigned r = x.u + 0x7fffu + ((x.u >> 16) & 1u);
    return (short)(r >> 16);
}

__device__ inline float fexp2(float f) { return __builtin_amdgcn_exp2f(f); }

// Barrier that does NOT drain outstanding global->VGPR loads (only LDS ops).
// __syncthreads() would emit s_waitcnt vmcnt(0) and collapse register prefetch.
__device__ inline void lds_barrier() {
    asm volatile("s_waitcnt lgkmcnt(0)\n\ts_barrier" ::: "memory");
}

// ---------------- W fp32 -> bf16 pre-convert. grid 768, block 256. Wbf[3][128][2048]
__global__ __launch_bounds__(256) void convw_kernel(
    const float* __restrict__ wq, const float* __restrict__ wk, const float* __restrict__ wv,
    short* __restrict__ Wbf)
{
    int idx = blockIdx.x * 256 + threadIdx.x;
    int mat = idx >> 16;
    int off = (idx & 65535) * 4;
    const float* W = (mat == 0) ? wq : (mat == 1) ? wk : wv;
    float4 v = *reinterpret_cast<const float4*>(W + off);
    short4v s = { f2bf(v.x), f2bf(v.y), f2bf(v.z), f2bf(v.w) };
    *reinterpret_cast<short4v*>(Wbf + (size_t)mat * DH * DM + off) = s;
}

// ---------------- Projection, split-K x4. grid (64, 3, 4), block 256 (4 waves).
// Block tile: 64 rows x 128 cols, K-range 512, BK=64 (8 chunks).
// Depth-4 A prefetch (HBM) + depth-2 W prefetch (L2) survive the K-loop
// because lds_barrier() does not drain vmcnt.
__global__ __launch_bounds__(256) void proj_kernel(
    const float* __restrict__ inq, const float* __restrict__ ink, const float* __restrict__ inv,
    const short* __restrict__ Wbf,
    float* __restrict__ Pqk, float* __restrict__ Pv)
{
    const int mat = blockIdx.y;
    const int s   = blockIdx.z;
    const float* A = (mat == 0) ? inq : (mat == 1) ? ink : inv;

    const int tid  = threadIdx.x;
    const int lane = tid & 63;
    const int w    = tid >> 6;
    const int g    = lane >> 4;
    const int c16  = lane & 15;
    const int i0   = blockIdx.x * 64;
    const int kb   = s * 512;

    __shared__ short Alds[64][72];
    __shared__ short Wlds[128][72];

    const int ar = tid >> 2, ac = (tid & 3) * 16;
    const float* Aload = A + (size_t)(i0 + ar) * DM + kb + ac;
    const int wr = tid >> 1, wc = (tid & 1) * 32;
    const short* Wload = Wbf + (size_t)mat * DH * DM + (size_t)wr * DM + kb + wc;

    f32x4 acc[2][4];
    #pragma unroll
    for (int mI = 0; mI < 2; mI++)
        #pragma unroll
        for (int n = 0; n < 4; n++) acc[mI][n] = (f32x4){0.f, 0.f, 0.f, 0.f};

    float4  abuf[4][4];   // depth 4
    bf16x8  wbuf[2][4];   // depth 2

    #pragma unroll
    for (int d = 0; d < 2; d++) {
        #pragma unroll
        for (int j = 0; j < 4; j++)
            wbuf[d][j] = *reinterpret_cast<const bf16x8*>(Wload + d * 64 + j * 8);
        #pragma unroll
        for (int j = 0; j < 4; j++)
            abuf[d][j] = *reinterpret_cast<const float4*>(Aload + d * 64 + j * 4);
    }
    #pragma unroll
    for (int d = 2; d < 4; d++)
        #pragma unroll
        for (int j = 0; j < 4; j++)
            abuf[d][j] = *reinterpret_cast<const float4*>(Aload + d * 64 + j * 4);

    const int rw = (w >> 1) * 32;
    const int cw = (w & 1) * 64;

    #pragma unroll
    for (int c = 0; c < 8; c++) {
        const int da = c & 3, dw = c & 1;
        {
            #pragma unroll
            for (int j = 0; j < 4; j++)
                *reinterpret_cast<bf16x8*>(&Wlds[wr][wc + j * 8]) = wbuf[dw][j];
            #pragma unroll
            for (int j = 0; j < 2; j++) {
                float4 v0 = abuf[da][j * 2], v1 = abuf[da][j * 2 + 1];
                bf16x8 sv = { f2bf(v0.x), f2bf(v0.y), f2bf(v0.z), f2bf(v0.w),
                              f2bf(v1.x), f2bf(v1.y), f2bf(v1.z), f2bf(v1.w) };
                *reinterpret_cast<bf16x8*>(&Alds[ar][ac + j * 8]) = sv;
            }
        }
        if (c + 2 < 8) {
            #pragma unroll
            for (int j = 0; j < 4; j++)
                wbuf[dw][j] = *reinterpret_cast<const bf16x8*>(Wload + (c + 2) * 64 + j * 8);
        }
        if (c + 4 < 8) {
            #pragma unroll
            for (int j = 0; j < 4; j++)
                abuf[da][j] = *reinterpret_cast<const float4*>(Aload + (c + 4) * 64 + j * 4);
        }
        lds_barrier();
        #pragma unroll
        for (int kk = 0; kk < 2; kk++) {
            bf16x8 af0 = *reinterpret_cast<const bf16x8*>(&Alds[rw + c16][kk * 32 + g * 8]);
            bf16x8 af1 = *reinterpret_cast<const bf16x8*>(&Alds[rw + 16 + c16][kk * 32 + g * 8]);
            #pragma unroll
            for (int n = 0; n < 4; n++) {
                bf16x8 wf = *reinterpret_cast<const bf16x8*>(
                    &Wlds[cw + n * 16 + c16][kk * 32 + g * 8]);
                acc[0][n] = __builtin_amdgcn_mfma_f32_16x16x32_bf16(af0, wf, acc[0][n], 0, 0, 0);
                acc[1][n] = __builtin_amdgcn_mfma_f32_16x16x32_bf16(af1, wf, acc[1][n], 0, 0, 0);
            }
        }
        lds_barrier();
    }

    if (mat < 2) {
        float* outp = Pqk + ((size_t)(mat * 4 + s) * SEQ) * DH;
        #pragma unroll
        for (int mI = 0; mI < 2; mI++) {
            int row0 = i0 + rw + mI * 16 + g * 4;
            #pragma unroll
            for (int n = 0; n < 4; n++) {
                int col = cw + n * 16 + c16;
                #pragma unroll
                for (int r = 0; r < 4; r++)
                    outp[(size_t)(row0 + r) * DH + col] = acc[mI][n][r];
            }
        }
    } else {
        float* outp = Pv + (size_t)s * DH * SEQ;
        #pragma unroll
        for (int mI = 0; mI < 2; mI++) {
            int row0 = i0 + rw + mI * 16 + g * 4;
            #pragma unroll
            for (int n = 0; n < 4; n++) {
                int col = cw + n * 16 + c16;
                float4 f = { acc[mI][n][0], acc[mI][n][1], acc[mI][n][2], acc[mI][n][3] };
                *reinterpret_cast<float4*>(&outp[(size_t)col * SEQ + row0]) = f;
            }
        }
    }
}

// ---------------- Combine 4 split-K partials + bias -> bf16 Q, K, Vt. grid 1536.
__global__ __launch_bounds__(256) void combine_kernel(
    const float* __restrict__ Pqk, const float* __restrict__ Pv,
    const float* __restrict__ bq, const float* __restrict__ bk, const float* __restrict__ bv,
    short* __restrict__ Qws, short* __restrict__ Kws, short* __restrict__ Vtws)
{
    const int b = blockIdx.x;
    if (b < 1024) {
        int tid = b * 256 + threadIdx.x;
        int mat = tid >> 17;
        int idx4 = (tid & 131071) * 4;
        float4 acc = {0.f, 0.f, 0.f, 0.f};
        #pragma unroll
        for (int s = 0; s < 4; s++) {
            float4 p = *reinterpret_cast<const float4*>(
                Pqk + ((size_t)(mat * 4 + s) * SEQ) * DH + idx4);
            acc.x += p.x; acc.y += p.y; acc.z += p.z; acc.w += p.w;
        }
        const float* bias = (mat == 0) ? bq : bk;
        int col = idx4 & (DH - 1);
        acc.x += bias[col]; acc.y += bias[col + 1]; acc.z += bias[col + 2]; acc.w += bias[col + 3];
        short4v o = { f2bf(acc.x), f2bf(acc.y), f2bf(acc.z), f2bf(acc.w) };
        short* outp = (mat == 0) ? Qws : Kws;
        *reinterpret_cast<short4v*>(outp + idx4) = o;
    } else {
        int tid = (b - 1024) * 256 + threadIdx.x;
        int idx4 = tid * 4;
        float4 acc = {0.f, 0.f, 0.f, 0.f};
        #pragma unroll
        for (int s = 0; s < 4; s++) {
            float4 p = *reinterpret_cast<const float4*>(Pv + (size_t)s * DH * SEQ + idx4);
            acc.x += p.x; acc.y += p.y; acc.z += p.z; acc.w += p.w;
        }
        float bvv = bv[idx4 >> 12];
        acc.x += bvv; acc.y += bvv; acc.z += bvv; acc.w += bvv;
        short4v o = { f2bf(acc.x), f2bf(acc.y), f2bf(acc.z), f2bf(acc.w) };
        *reinterpret_cast<short4v*>(Vtws + idx4) = o;
    }
}

// ---------------- Flash attention, block-cooperative K/V staging, vmcnt-preserving
// barriers. grid (64, NSPLIT), block 256 (4 waves).
__global__ __launch_bounds__(256) void flash_kernel(
    const short* __restrict__ Qws, const short* __restrict__ Kws, const short* __restrict__ Vtws,
    float* __restrict__ Opart, float* __restrict__ mpart, float* __restrict__ lpart)
{
    const int qb = blockIdx.x;
    const int y  = blockIdx.y;
    const int tid = threadIdx.x;
    const int w    = tid >> 6;
    const int lane = tid & 63;
    const int g = lane >> 4, c16 = lane & 15;
    const int i0 = qb * 64 + w * 16;

    __shared__ short Klds[64][136];
    __shared__ short Vlds[128][72];
    __shared__ short Slds[4][16][72];

    const int kkey = tid >> 2,  kdim = (tid & 3) * 32;
    const int vdim = tid >> 1,  vkey = (tid & 1) * 32;

    bf16x8 kreg[4], vreg[4];

    bf16x8 qf[4];
    #pragma unroll
    for (int kk = 0; kk < 4; kk++)
        qf[kk] = *reinterpret_cast<const bf16x8*>(Qws + (size_t)(i0 + c16) * DH + kk * 32 + g * 8);

    float m[4], lsum[4];
    f32x4 O[8];
    #pragma unroll
    for (int r = 0; r < 4; r++) { m[r] = -__builtin_inff(); lsum[r] = 0.f; }
    #pragma unroll
    for (int c = 0; c < 8; c++) O[c] = (f32x4){0.f, 0.f, 0.f, 0.f};

    const float C = 0.03188448666f;      // log2(e)/sqrt(2048)

    if (qb >= y) {
        {
            const int j0 = y * 64;
            #pragma unroll
            for (int j = 0; j < 4; j++) {
                kreg[j] = *reinterpret_cast<const bf16x8*>(
                    Kws + (size_t)(j0 + kkey) * DH + kdim + j * 8);
                vreg[j] = *reinterpret_cast<const bf16x8*>(
                    Vtws + (size_t)vdim * SEQ + j0 + vkey + j * 8);
            }
            #pragma unroll
            for (int j = 0; j < 4; j++) {
                *reinterpret_cast<bf16x8*>(&Klds[kkey][kdim + j * 8]) = kreg[j];
                *reinterpret_cast<bf16x8*>(&Vlds[vdim][vkey + j * 8]) = vreg[j];
            }
        }
        lds_barrier();

        for (int jt = y; jt <= qb; jt += NSPLIT) {
            const bool more = (jt + NSPLIT <= qb);
            if (more) {
                const int jn = (jt + NSPLIT) * 64;
                #pragma unroll
                for (int j = 0; j < 4; j++) {
                    kreg[j] = *reinterpret_cast<const bf16x8*>(
                        Kws + (size_t)(jn + kkey) * DH + kdim + j * 8);
                    vreg[j] = *reinterpret_cast<const bf16x8*>(
                        Vtws + (size_t)vdim * SEQ + jn + vkey + j * 8);
                }
            }
            const int j0 = jt * 64;
            f32x4 S[4];
            #pragma unroll
            for (int t = 0; t < 4; t++) S[t] = (f32x4){0.f, 0.f, 0.f, 0.f};
            #pragma unroll
            for (int kk = 0; kk < 4; kk++) {
                #pragma unroll
                for (int t = 0; t < 4; t++) {
                    bf16x8 kf = *reinterpret_cast<const bf16x8*>(
                        &Klds[t * 16 + c16][kk * 32 + g * 8]);
                    S[t] = __builtin_amdgcn_mfma_f32_16x16x32_bf16(qf[kk], kf, S[t], 0, 0, 0);
                }
            }
            float s2[4][4];
            #pragma unroll
            for (int t = 0; t < 4; t++) {
                int key = j0 + t * 16 + c16;
                #pragma unroll
                for (int r = 0; r < 4; r++) {
                    int q = i0 + g * 4 + r;
                    s2[t][r] = (key > q) ? -__builtin_inff() : S[t][r] * C;
                }
            }
            float mnew[4], alpha[4];
            #pragma unroll
            for (int r = 0; r < 4; r++) {
                float rm = fmaxf(fmaxf(s2[0][r], s2[1][r]), fmaxf(s2[2][r], s2[3][r]));
                rm = fmaxf(rm, __shfl_xor(rm, 1));
                rm = fmaxf(rm, __shfl_xor(rm, 2));
                rm = fmaxf(rm, __shfl_xor(rm, 4));
                rm = fmaxf(rm, __shfl_xor(rm, 8));
                mnew[r] = fmaxf(m[r], rm);
                alpha[r] = fexp2(m[r] - mnew[r]);
                m[r] = mnew[r];
            }
            #pragma unroll
            for (int r = 0; r < 4; r++) {
                float ps = 0.f;
                #pragma unroll
                for (int t = 0; t < 4; t++) {
                    float p = fexp2(s2[t][r] - mnew[r]);
                    ps += p;
                    Slds[w][g * 4 + r][t * 16 + c16] = f2bf(p);
                }
                ps += __shfl_xor(ps, 1);
                ps += __shfl_xor(ps, 2);
                ps += __shfl_xor(ps, 4);
                ps += __shfl_xor(ps, 8);
                lsum[r] = lsum[r] * alpha[r] + ps;
                #pragma unroll
                for (int c = 0; c < 8; c++) O[c][r] *= alpha[r];
            }
            #pragma unroll
            for (int kk2 = 0; kk2 < 2; kk2++) {
                bf16x8 pf = *reinterpret_cast<const bf16x8*>(&Slds[w][c16][kk2 * 32 + g * 8]);
                #pragma unroll
                for (int c = 0; c < 8; c++) {
                    bf16x8 vf = *reinterpret_cast<const bf16x8*>(
                        &Vlds[c * 16 + c16][kk2 * 32 + g * 8]);
                    O[c] = __builtin_amdgcn_mfma_f32_16x16x32_bf16(pf, vf, O[c], 0, 0, 0);
                }
            }
            lds_barrier();               // readers done with Klds/Vlds
            if (more) {
                #pragma unroll
                for (int j = 0; j < 4; j++) {
                    *reinterpret_cast<bf16x8*>(&Klds[kkey][kdim + j * 8]) = kreg[j];
                    *reinterpret_cast<bf16x8*>(&Vlds[vdim][vkey + j * 8]) = vreg[j];
                }
                lds_barrier();           // writes visible before next compute
            }
        }
        #pragma unroll
        for (int c = 0; c < 8; c++) {
            int col = c * 16 + c16;
            #pragma unroll
            for (int r = 0; r < 4; r++)
                Opart[((size_t)y * SEQ + i0 + g * 4 + r) * DH + col] = O[c][r];
        }
    }
    if (c16 == 0) {
        #pragma unroll
        for (int r = 0; r < 4; r++) {
            mpart[y * SEQ + i0 + g * 4 + r] = m[r];
            lpart[y * SEQ + i0 + g * 4 + r] = lsum[r];
        }
    }
}

// ---------------- Merge NS split partials. grid 2048, block 256 (2 rows/block).
__global__ __launch_bounds__(256) void merge_kernel(
    const float* __restrict__ Opart, const float* __restrict__ mpart, const float* __restrict__ lpart,
    float* __restrict__ out, int NS)
{
    const int row = blockIdx.x * 2 + (threadIdx.x >> 7);
    const int col = threadIdx.x & 127;
    float mh[16];
    float M = -__builtin_inff();
    for (int hh = 0; hh < NS; hh++) {
        mh[hh] = mpart[hh * SEQ + row];
        M = fmaxf(M, mh[hh]);
    }
    float denom = 0.f, num = 0.f;
    for (int hh = 0; hh < NS; hh++) {
        float wgt = fexp2(mh[hh] - M);
        denom += lpart[hh * SEQ + row] * wgt;
        num   += Opart[((size_t)hh * SEQ + row) * DH + col] * wgt;
    }
    out[(size_t)row * DH + col] = num / denom;
}

extern "C" void kernel_launch(void* const* d_in, const int* in_sizes, int n_in,
                              void* d_out, int out_size, void* d_ws, size_t ws_size,
                              hipStream_t stream) {
    const float* inq = (const float*)d_in[0];
    const float* ink = (const float*)d_in[1];
    const float* inv = (const float*)d_in[2];
    const float* wq  = (const float*)d_in[3];
    const float* bq  = (const float*)d_in[4];
    const float* wk  = (const float*)d_in[5];
    const float* bk  = (const float*)d_in[6];
    const float* wv  = (const float*)d_in[7];
    const float* bv  = (const float*)d_in[8];

    char* ws = (char*)d_ws;
    short* Qws   = (short*)(ws);                         // [0, 1 MB)
    short* Kws   = (short*)(ws + (1u << 20));            // [1, 2 MB)
    short* Vtws  = (short*)(ws + (2u << 20));            // [2, 3 MB)  ([128][4096])
    short* Wbf   = (short*)(ws + (3u << 20));            // [3, 4.5 MB) bf16 W (proj-only)
    float* Pqk   = (float*)(ws + 4718592);               // [4.5, 20.5 MB)
    float* Pv    = (float*)(ws + 21495808);              // [20.5, 28.5 MB)
    float* Opart = (float*)(ws + (3u << 20));            // aliases Wbf/Pqk (dead by flash)
    float* mpart = (float*)(ws + (3u << 20) + (size_t)NSPLIT * SEQ * DH * 4);
    float* lpart = mpart + (size_t)NSPLIT * SEQ;

    convw_kernel<<<768, 256, 0, stream>>>(wq, wk, wv, Wbf);
    proj_kernel<<<dim3(64, 3, 4), 256, 0, stream>>>(inq, ink, inv, Wbf, Pqk, Pv);
    combine_kernel<<<1536, 256, 0, stream>>>(Pqk, Pv, bq, bk, bv, Qws, Kws, Vtws);
    flash_kernel<<<dim3(64, NSPLIT), 256, 0, stream>>>(Qws, Kws, Vtws, Opart, mpart, lpart);
    merge_kernel<<<2048, 256, 0, stream>>>(Opart, mpart, lpart, (float*)d_out, NSPLIT);
}